// Round 2
// baseline (236.654 us; speedup 1.0000x reference)
//
#include <hip/hip_runtime.h>

// QuantizedLinear(5, 10, bits=2): out[N,10] = x[N,5] @ w_deq.T + bias
// Memory-bound streaming: 80 MB read + 160 MB write, floor ~38 us @ 6.3 TB/s.
//
// R1 (225 us, 1.07 TB/s) was phase-serialized: 60 KB LDS -> 2 blocks/CU,
// load->sync->compute->sync->store lockstep. R2: no bulk LDS, no output
// staging, 2 tokens/thread, direct lane-strided float2 loads / float4 stores
// (L2 write-back merges adjacent-lane partial lines), weights broadcast from
// a 240 B LDS table.

constexpr int IN_F  = 5;
constexpr int OUT_F = 10;
constexpr int BLOCK = 256;

__global__ __launch_bounds__(BLOCK) void qlinear_kernel(
    const float* __restrict__ x,
    const float* __restrict__ w,
    const float* __restrict__ bias,
    float* __restrict__ out,
    int n_pairs)           // n_tokens / 2 (pairs of tokens per thread)
{
    __shared__ float wdq[OUT_F * IN_F];
    __shared__ float bsh[OUT_F];

    // threads 0..9 dequantize one output row each (bits=2: qmax=1, qmin=-2)
    if (threadIdx.x < OUT_F) {
        const int o = threadIdx.x;
        float row[IN_F];
        float mx = 0.0f;
        #pragma unroll
        for (int j = 0; j < IN_F; ++j) {
            row[j] = w[o * IN_F + j];
            mx = fmaxf(mx, fabsf(row[j]));
        }
        const float scale = fmaxf(mx, 1e-8f);
        #pragma unroll
        for (int j = 0; j < IN_F; ++j) {
            float q = rintf(row[j] / scale);        // round-half-even like jnp
            q = fminf(fmaxf(q, -2.0f), 1.0f);
            wdq[o * IN_F + j] = q * scale;
        }
        bsh[o] = bias[o];
    }
    __syncthreads();

    const int p = blockIdx.x * BLOCK + threadIdx.x;
    if (p >= n_pairs) return;

    // --- load 2 tokens (10 floats) as 5x float2, lane stride 40 B ---
    const float2* __restrict__ xg = (const float2*)(x + (long)p * (2 * IN_F));
    float xv[2 * IN_F];
    #pragma unroll
    for (int k = 0; k < IN_F; ++k) {
        float2 v = xg[k];
        xv[2 * k]     = v.x;
        xv[2 * k + 1] = v.y;
    }

    // --- compute 2 x 10 outputs; weights broadcast from LDS ---
    float o0[OUT_F], o1[OUT_F];
    #pragma unroll
    for (int o = 0; o < OUT_F; ++o) {
        float a0 = bsh[o];
        float a1 = a0;
        #pragma unroll
        for (int j = 0; j < IN_F; ++j) {
            const float wv = wdq[o * IN_F + j];
            a0 = fmaf(xv[j],         wv, a0);
            a1 = fmaf(xv[IN_F + j],  wv, a1);
        }
        o0[o] = a0;
        o1[o] = a1;
    }

    // --- store 20 floats as 5x float4, lane stride 80 B (contiguous per pair) ---
    float4* __restrict__ og = (float4*)(out + (long)p * (2 * OUT_F));
    og[0] = make_float4(o0[0], o0[1], o0[2], o0[3]);
    og[1] = make_float4(o0[4], o0[5], o0[6], o0[7]);
    og[2] = make_float4(o0[8], o0[9], o1[0], o1[1]);
    og[3] = make_float4(o1[2], o1[3], o1[4], o1[5]);
    og[4] = make_float4(o1[6], o1[7], o1[8], o1[9]);
}

extern "C" void kernel_launch(void* const* d_in, const int* in_sizes, int n_in,
                              void* d_out, int out_size, void* d_ws, size_t ws_size,
                              hipStream_t stream) {
    const float* x    = (const float*)d_in[0];   // [N, 5]
    const float* wgt  = (const float*)d_in[1];   // [10, 5]
    const float* bias = (const float*)d_in[2];   // [10]
    float* out = (float*)d_out;                  // [N, 10]

    const int n_tokens = in_sizes[0] / IN_F;     // 4,000,000 (even)
    const int n_pairs  = n_tokens / 2;           // 2,000,000
    const int blocks   = (n_pairs + BLOCK - 1) / BLOCK;  // 7813

    qlinear_kernel<<<blocks, BLOCK, 0, stream>>>(x, wgt, bias, out, n_pairs);
}

// Round 3
// 212.433 us; speedup vs baseline: 1.1140x; 1.1140x over previous
//
#include <hip/hip_runtime.h>

// QuantizedLinear(5, 10, bits=2): out[N,10] = x[N,5] @ w_deq.T + bias
// Memory-bound: 80 MB read + 160 MB write -> ~38 us floor @ 6.3 TB/s.
//
// R1 (225 us): coalesced LDS-staged, but 60 KB LDS -> 2 blocks/CU, phases
//   serialized. R2 (237 us): direct lane-strided loads/stores -> 5x the
//   memory transactions per byte (13 B useful/txn), worse.
// R3: coalesced everywhere like R1, but 256-token tiles -> 15 KB LDS ->
//   8 blocks/CU (100% occupancy), 15625 blocks; per-thread work = 1 token.
//   Nontemporal global access (240 MB stream >> 32 MB L2).

constexpr int IN_F  = 5;
constexpr int OUT_F = 10;
constexpr int BLOCK = 256;
constexpr int TOK   = 256;           // tokens per block == threads per block

__global__ __launch_bounds__(BLOCK) void qlinear_kernel(
    const float* __restrict__ x,
    const float* __restrict__ w,
    const float* __restrict__ bias,
    float* __restrict__ out,
    int n_tokens)
{
    __shared__ float wdq[OUT_F * IN_F];
    __shared__ float bsh[OUT_F];
    __shared__ float xs[TOK * IN_F];     // 5 KB
    __shared__ float os[TOK * OUT_F];    // 10 KB

    const int tid = threadIdx.x;

    // threads 0..9: dequantize one weight row each (bits=2: qmax=1, qmin=-2)
    if (tid < OUT_F) {
        float row[IN_F];
        float mx = 0.0f;
        #pragma unroll
        for (int j = 0; j < IN_F; ++j) {
            row[j] = w[tid * IN_F + j];
            mx = fmaxf(mx, fabsf(row[j]));
        }
        const float scale = fmaxf(mx, 1e-8f);
        #pragma unroll
        for (int j = 0; j < IN_F; ++j) {
            float q = rintf(row[j] / scale);       // round-half-even like jnp
            q = fminf(fmaxf(q, -2.0f), 1.0f);
            wdq[tid * IN_F + j] = q * scale;
        }
        bsh[tid] = bias[tid];
    }

    const long tok0 = (long)blockIdx.x * TOK;
    const bool full = (tok0 + TOK) <= (long)n_tokens;
    const long xbase = tok0 * IN_F;
    const long obase = tok0 * OUT_F;

    // --- stage x tile: 1280 floats, 5 coalesced dword loads/thread ---
    if (full) {
        #pragma unroll
        for (int i = 0; i < IN_F; ++i) {
            const int k = i * BLOCK + tid;
            xs[k] = __builtin_nontemporal_load(x + xbase + k);
        }
    } else {
        const long xtotal = (long)n_tokens * IN_F;
        #pragma unroll
        for (int i = 0; i < IN_F; ++i) {
            const int k = i * BLOCK + tid;
            const long gi = xbase + k;
            xs[k] = (gi < xtotal) ? x[gi] : 0.0f;
        }
    }
    __syncthreads();

    // --- compute: 1 token/thread; xs read stride 5 (odd, conflict-free) ---
    {
        float xv[IN_F];
        #pragma unroll
        for (int j = 0; j < IN_F; ++j) xv[j] = xs[tid * IN_F + j];
        #pragma unroll
        for (int o = 0; o < OUT_F; ++o) {
            float acc = bsh[o];
            #pragma unroll
            for (int j = 0; j < IN_F; ++j)
                acc = fmaf(xv[j], wdq[o * IN_F + j], acc);
            os[tid * OUT_F + o] = acc;   // 4-way bank conflict, negligible
        }
    }
    __syncthreads();

    // --- store out tile: 2560 floats, 10 coalesced dword stores/thread ---
    if (full) {
        #pragma unroll
        for (int i = 0; i < OUT_F; ++i) {
            const int k = i * BLOCK + tid;
            __builtin_nontemporal_store(os[k], out + obase + k);
        }
    } else {
        const long ototal = (long)n_tokens * OUT_F;
        #pragma unroll
        for (int i = 0; i < OUT_F; ++i) {
            const int k = i * BLOCK + tid;
            const long gi = obase + k;
            if (gi < ototal) out[gi] = os[k];
        }
    }
}

extern "C" void kernel_launch(void* const* d_in, const int* in_sizes, int n_in,
                              void* d_out, int out_size, void* d_ws, size_t ws_size,
                              hipStream_t stream) {
    const float* x    = (const float*)d_in[0];   // [N, 5]
    const float* wgt  = (const float*)d_in[1];   // [10, 5]
    const float* bias = (const float*)d_in[2];   // [10]
    float* out = (float*)d_out;                  // [N, 10]

    const int n_tokens = in_sizes[0] / IN_F;     // 4,000,000
    const int blocks   = (n_tokens + TOK - 1) / TOK;  // 15625, no tail

    qlinear_kernel<<<blocks, BLOCK, 0, stream>>>(x, wgt, bias, out, n_tokens);
}